// Round 19
// baseline (453.768 us; speedup 1.0000x reference)
//
#include <hip/hip_runtime.h>
#include <math.h>

// B=8, C=128, H=128, W=128, D_INNER=256, D_STATE=64, HEADDIM=32, NHEADS=8,
// D_CONV=4, GN_GROUPS=8, D_XBC=384, D_INPROJ=648.
// Inputs f32 (probed via gn_g word0). OUTPUT IS F32 (reference output dtype).
// d_out = [out_2d: 16,777,216 f32][offset: 131,072 f32].
// h1 (f16) is staged in d_out's out_2d region.
//
// R10 SSD matrix scan 679 -> R11 conv1d into gemm1 594 -> R14 gn_part 494 ->
// R15 gate into ssd 469 -> R17 factorized decay 468 -> R18 gemm1 BN=256 450.
// R19: ssd v5 - 512-thread block, head-parallel WAVE-GROUPS (group g = heads
// g*4..g*4+3); G computed once by 8 waves (16 rows each) and SHARED (R16's
// cross-block split duplicated G and didn't raise occupancy); per-group
// Xt/ejs; partial sumsq combined via LDS (reuses dead Ts). LDS 57.3KB -> 2
// blk x 8 waves = 16 waves/CU (was 8). ssd was latency-bound at occupancy 17%.

typedef _Float16 half8 __attribute__((ext_vector_type(8)));
typedef _Float16 half4 __attribute__((ext_vector_type(4)));
typedef float f32x4 __attribute__((ext_vector_type(4)));

__device__ __forceinline__ float b2f(unsigned short u) {
  return __uint_as_float(((unsigned int)u) << 16);
}
__device__ __forceinline__ bool in_is_f32(const void* gng) {
  return ((const unsigned int*)gng)[0] == 0x3F800000u;
}

#define P_DWW 0
#define P_CW 3200
#define P_CB 4736
#define P_GNG 5120
#define P_GNB 5248
#define P_PWW 5376
#define P_PWB 5504
#define P_DTB 5505
#define P_ALOG 5513
#define P_DSKIP 5521
#define P_NG 5529

// ---------------- P0: all prep in one launch ------------------------------------
__global__ void k_prep_all(const void* dww, const void* cw, const void* cb,
                           const void* gng, const void* gnb, const void* pww,
                           const void* pwb, const void* dtbias, const void* alog,
                           const void* dskip, const void* ng,
                           const void* wproj, const void* outw,
                           float* __restrict__ P, float* __restrict__ gst,
                           _Float16* __restrict__ wprojh, _Float16* __restrict__ outwh) {
  bool f = in_is_f32(gng);
  int stride = gridDim.x * blockDim.x;
  for (int i = blockIdx.x * blockDim.x + threadIdx.x; i < 98304; i += stride) {
    int row = i >> 7;
    float v = 0.f;
    if (row < 648) v = f ? ((const float*)wproj)[i] : b2f(((const unsigned short*)wproj)[i]);
    wprojh[i] = (_Float16)v;
  }
  for (int i = blockIdx.x * blockDim.x + threadIdx.x; i < 32768; i += stride) {
    int e = i & 255;
    float wv = f ? ((const float*)outw)[i] : b2f(((const unsigned short*)outw)[i]);
    float ngv = f ? ((const float*)ng)[e] : b2f(((const unsigned short*)ng)[e]);
    outwh[i] = (_Float16)(wv * ngv);
  }
  if (blockIdx.x == 0) {
    int tid = threadIdx.x;
    if (tid < 128) gst[tid] = 0.f;
    auto cvt = [&](const void* src, int n, int off) {
      for (int i = tid; i < n; i += 256)
        P[off + i] = f ? ((const float*)src)[i] : b2f(((const unsigned short*)src)[i]);
    };
    cvt(dww, 3200, P_DWW);
    cvt(cw, 1536, P_CW);
    cvt(cb, 384, P_CB);
    cvt(gng, 128, P_GNG);
    cvt(gnb, 128, P_GNB);
    cvt(pww, 128, P_PWW);
    cvt(pwb, 1, P_PWB);
    cvt(dtbias, 8, P_DTB);
    cvt(alog, 8, P_ALOG);
    cvt(dskip, 8, P_DSKIP);
    cvt(ng, 256, P_NG);
  }
}

// ---------------- K1 v6: depthwise 5x5 conv + group stats, NO LDS ---------------
__global__ __launch_bounds__(256) void k_dwconv_v6(const void* __restrict__ x,
                                                   const void* __restrict__ gng,
                                                   const float* __restrict__ P,
                                                   _Float16* __restrict__ h1h,
                                                   float* __restrict__ gst) {
  int bc = blockIdx.x;
  int b = bc >> 7, c = bc & 127;
  bool f32x = in_is_f32(gng);
  __shared__ float red[8];
  const float* xf = (const float*)x + (size_t)bc * 16384;
  const unsigned short* xb = (const unsigned short*)x + (size_t)bc * 16384;
  float w[25];
#pragma unroll
  for (int k = 0; k < 25; ++k) w[k] = P[P_DWW + c * 25 + k];

  int ox = (threadIdx.x & 31) * 4;   // 0..124
  int y0 = (threadIdx.x >> 5) * 16;  // 0..112
  float win[5][12];

  auto loadrow = [&](int gy, float* d) {
#pragma unroll
    for (int k = 0; k < 12; ++k) d[k] = 0.f;
    if (gy >= 0 && gy < 128) {
      if (f32x) {
        const float* rp = xf + gy * 128;
        if (ox >= 4) {
          float4 v = *(const float4*)(rp + ox - 4);
          d[0] = v.x; d[1] = v.y; d[2] = v.z; d[3] = v.w;
        }
        float4 v0 = *(const float4*)(rp + ox);
        d[4] = v0.x; d[5] = v0.y; d[6] = v0.z; d[7] = v0.w;
        if (ox < 124) {
          float4 v1 = *(const float4*)(rp + ox + 4);
          d[8] = v1.x; d[9] = v1.y; d[10] = v1.z; d[11] = v1.w;
        }
      } else {
        const unsigned short* rp = xb + gy * 128;
        if (ox >= 4) {
          ushort4 u = *(const ushort4*)(rp + ox - 4);
          d[0] = b2f(u.x); d[1] = b2f(u.y); d[2] = b2f(u.z); d[3] = b2f(u.w);
        }
        ushort4 u0 = *(const ushort4*)(rp + ox);
        d[4] = b2f(u0.x); d[5] = b2f(u0.y); d[6] = b2f(u0.z); d[7] = b2f(u0.w);
        if (ox < 124) {
          ushort4 u1 = *(const ushort4*)(rp + ox + 4);
          d[8] = b2f(u1.x); d[9] = b2f(u1.y); d[10] = b2f(u1.z); d[11] = b2f(u1.w);
        }
      }
    }
  };

#pragma unroll
  for (int i = 0; i < 4; ++i) loadrow(y0 - 2 + i, win[i]);

  float s = 0.f, sq = 0.f;
  _Float16* hp = h1h + (size_t)bc * 16384;
#pragma unroll
  for (int yo = 0; yo < 16; ++yo) {
    loadrow(y0 + yo + 2, win[(yo + 4) % 5]);
    float o4[4] = {0.f, 0.f, 0.f, 0.f};
#pragma unroll
    for (int ky = 0; ky < 5; ++ky) {
      const float* r = win[(yo + ky) % 5];
#pragma unroll
      for (int j = 0; j < 4; ++j)
#pragma unroll
        for (int kx = 0; kx < 5; ++kx)
          o4[j] += w[ky * 5 + kx] * r[j + kx + 2];
    }
    half4 oh;
#pragma unroll
    for (int j = 0; j < 4; ++j) {
      oh[j] = (_Float16)o4[j];
      s += o4[j]; sq += o4[j] * o4[j];
    }
    *(half4*)&hp[(y0 + yo) * 128 + ox] = oh;
  }

  for (int o = 32; o; o >>= 1) { s += __shfl_down(s, o, 64); sq += __shfl_down(sq, o, 64); }
  int wv = threadIdx.x >> 6;
  if ((threadIdx.x & 63) == 0) { red[wv] = s; red[4 + wv] = sq; }
  __syncthreads();
  if (threadIdx.x == 0) {
    float ts = red[0] + red[1] + red[2] + red[3];
    float tq = red[4] + red[5] + red[6] + red[7];
    int g = (b << 3) + (c >> 4);
    atomicAdd(&gst[g * 2], ts);
    atomicAdd(&gst[g * 2 + 1], tq);
  }
}

// ---------------- K3 v5: GN + GELU + 1x1 conv PARTIAL ---------------------------
__global__ __launch_bounds__(256) void k_gn_part(const _Float16* __restrict__ h1h,
                                                 const float* __restrict__ gst,
                                                 const float* __restrict__ P,
                                                 float* __restrict__ part) {
  int bh2 = blockIdx.x;
  int b = bh2 >> 8;
  int h = (bh2 & 255) >> 1;
  int half = bh2 & 1;
  int tid = threadIdx.x;
  int w = tid & 127;
  int sub = tid >> 7;
  __shared__ float ls[8];
  __shared__ float sacc[2][128];
  if (tid < 4) {
    const float invN = 1.f / 262144.f;
    int g = b * 8 + half * 4 + tid;
    float mean = gst[g * 2] * invN;
    float var = gst[g * 2 + 1] * invN - mean * mean;
    ls[tid * 2] = mean;
    ls[tid * 2 + 1] = rsqrtf(var + 1e-5f);
  }
  __syncthreads();
  int cbase = half * 64 + sub * 32;
  const _Float16* hb = h1h + (((size_t)(b * 128 + cbase)) * 128 + h) * 128 + w;
  float acc = 0.f;
#pragma unroll 4
  for (int ci = 0; ci < 32; ++ci) {
    int c = cbase + ci;
    float v = (float)hb[(size_t)ci * 16384];
    int lg = (sub * 32 + ci) >> 4;
    float nv = (v - ls[lg * 2]) * ls[lg * 2 + 1] * P[P_GNG + c] + P[P_GNB + c];
    float ge = 0.5f * nv * (1.f + erff(nv * 0.70710678118f));
    acc += ge * P[P_PWW + c];
  }
  sacc[sub][w] = acc;
  __syncthreads();
  if (sub == 0) part[(size_t)bh2 * 128 + w] = acc + sacc[1][w];
}

// ---------------- K4 v5: deform (combines gn partials + tanh), 2 ch/iter --------
__global__ __launch_bounds__(256) void k_deform_v5(const void* __restrict__ x,
                                                   const void* __restrict__ gng,
                                                   const float* __restrict__ part,
                                                   const float* __restrict__ P,
                                                   _Float16* __restrict__ seqc,
                                                   float* __restrict__ dout,
                                                   int s0) {
  int bh = s0 + blockIdx.x;
  int b = bh >> 7, h = bh & 127;
  int tid = threadIdx.x;
  int w = tid & 127;
  int half = tid >> 7;
  bool f32x = in_is_f32(gng);
  __shared__ float t[128 * 129];
  float ofv = tanhf(part[(size_t)bh * 256 + w] + part[(size_t)bh * 256 + 128 + w] +
                    P[P_PWB]) * 8.0f;
  if (half == 0) dout[16777216 + bh * 128 + w] = ofv;
  float gy = -1.f + (2.f / 127.f) * (float)h + ofv * (2.f / 127.f);
  gy = fminf(fmaxf(gy, -1.f), 1.f);
  float py = (gy + 1.f) * 0.5f * 127.f;
  py = fminf(fmaxf(py, 0.f), 127.f);
  float y0f = floorf(py);
  float wy = py - y0f;
  int y0 = (int)y0f;
  int y1 = min(y0 + 1, 127);
  const float* xfb = (const float*)x + (size_t)b * 128 * 16384;
  const unsigned short* xbb = (const unsigned short*)x + (size_t)b * 128 * 16384;
  int c0 = half * 64;
  for (int i = 0; i < 64; i += 2) {
    int ca = c0 + i, cb2 = c0 + i + 1;
    size_t a0 = (size_t)ca * 16384 + y0 * 128 + w;
    size_t a1 = (size_t)ca * 16384 + y1 * 128 + w;
    size_t b0 = (size_t)cb2 * 16384 + y0 * 128 + w;
    size_t b1 = (size_t)cb2 * 16384 + y1 * 128 + w;
    float va0, va1, vb0, vb1;
    if (f32x) { va0 = xfb[a0]; va1 = xfb[a1]; vb0 = xfb[b0]; vb1 = xfb[b1]; }
    else      { va0 = b2f(xbb[a0]); va1 = b2f(xbb[a1]);
                vb0 = b2f(xbb[b0]); vb1 = b2f(xbb[b1]); }
    t[ca * 129 + w] = va0 + wy * (va1 - va0);
    t[cb2 * 129 + w] = vb0 + wy * (vb1 - vb0);
  }
  __syncthreads();
  int c2 = tid & 127;
  int lb = (tid >> 7) * 64;
  _Float16* sp = seqc + (size_t)blockIdx.x * 16384;
  for (int i = 0; i < 64; ++i) {
    int l = lb + i;
    sp[l * 128 + c2] = (_Float16)t[c2 * 129 + l];
  }
}

// ---------------- G1 v8: BN=256, 512 thr, shared A staging, dt fast path --------
__global__ __launch_bounds__(512) void k_gemm1_v8(const _Float16* __restrict__ seqh,
                                                  const _Float16* __restrict__ wprojh,
                                                  const float* __restrict__ P,
                                                  _Float16* __restrict__ zh,
                                                  _Float16* __restrict__ xch,
                                                  float* __restrict__ dtb) {
  __shared__ __align__(16) _Float16 lds[33792];   // lA(8192)|lB(16384) or sx 2x16896
  _Float16* lA = lds;
  _Float16* lB = lds + 8192;
  int m0 = blockIdx.x * 128;
  int e0 = blockIdx.y * 256;
  int tid = threadIdx.x;
  int lane = tid & 63;
  int wv = tid >> 6;          // 0..7
  int grp = tid >> 8;         // 0/1
  int wvl = wv & 3;           // wave within group
  int rsel = lane & 15, q = lane >> 4;
  bool isz = (e0 == 0);
  bool isdt = (e0 == 512) && (grp == 1);

  f32x4 acc[2][8];
#pragma unroll
  for (int rf = 0; rf < 2; ++rf)
#pragma unroll
    for (int cf = 0; cf < 8; ++cf) acc[rf][cf] = (f32x4){0.f, 0.f, 0.f, 0.f};

  for (int k0 = 0; k0 < 128; k0 += 64) {
    if (k0) __syncthreads();
#pragma unroll
    for (int p = 0; p < 2; ++p) {
      int idx = tid + 512 * p;
      int row = idx >> 3, ch = idx & 7;
      int dch = ch ^ (row & 7);
      *(half8*)&lA[row * 64 + dch * 8] =
          *(const half8*)&seqh[(size_t)(m0 + row) * 128 + k0 + ch * 8];
    }
#pragma unroll
    for (int p = 0; p < 4; ++p) {
      int idx = tid + 512 * p;
      int row = idx >> 3, ch = idx & 7;
      int dch = ch ^ (row & 7);
      *(half8*)&lB[row * 64 + dch * 8] =
          *(const half8*)&wprojh[(size_t)(e0 + row) * 128 + k0 + ch * 8];
    }
    __syncthreads();
#pragma unroll
    for (int kk = 0; kk < 2; ++kk) {
      half8 a[2];
#pragma unroll
      for (int rf = 0; rf < 2; ++rf) {
        int row = wvl * 32 + rf * 16 + rsel;
        int ch = (kk * 4 + q) ^ (row & 7);
        a[rf] = *(const half8*)&lA[row * 64 + ch * 8];
      }
#pragma unroll
      for (int cf = 0; cf < 8; ++cf) {
        if (isdt && cf > 0) continue;
        int row = grp * 128 + cf * 16 + rsel;
        int ch = (kk * 4 + q) ^ (row & 7);
        half8 b = *(const half8*)&lB[row * 64 + ch * 8];
        acc[0][cf] = __builtin_amdgcn_mfma_f32_16x16x32_f16(a[0], b, acc[0][cf], 0, 0, 0);
        acc[1][cf] = __builtin_amdgcn_mfma_f32_16x16x32_f16(a[1], b, acc[1][cf], 0, 0, 0);
      }
    }
  }

  __syncthreads();
  _Float16* sx = lds + grp * 16896;   // [128][132]
  if (!isz && !isdt) {
#pragma unroll
    for (int rf = 0; rf < 2; ++rf) {
#pragma unroll
      for (int r = 0; r < 4; ++r) {
        int row = wvl * 32 + rf * 16 + q * 4 + r;
#pragma unroll
        for (int cf = 0; cf < 8; ++cf)
          sx[row * 132 + cf * 16 + rsel] = (_Float16)acc[rf][cf][r];
      }
    }
  }
  __syncthreads();

  if (isz) {
#pragma unroll
    for (int rf = 0; rf < 2; ++rf) {
      int mb = m0 + wvl * 32 + rf * 16 + q * 4;
#pragma unroll
      for (int cf = 0; cf < 8; ++cf) {
        _Float16* pz = zh + (size_t)mb * 256 + grp * 128 + cf * 16 + rsel;
#pragma unroll
        for (int r = 0; r < 4; ++r) pz[(size_t)r * 256] = (_Float16)acc[rf][cf][r];
      }
    }
  } else if (isdt) {
#pragma unroll
    for (int rf = 0; rf < 2; ++rf) {
      int mb = m0 + wvl * 32 + rf * 16 + q * 4;
      if (rsel < 8) {
        float bias = P[P_DTB + rsel];
#pragma unroll
        for (int r = 0; r < 4; ++r) {
          float dv = acc[rf][0][r] + bias;
          float sp = (dv > 20.f) ? dv : log1pf(__expf(dv));
          dtb[(size_t)(mb + r) * 8 + rsel] = sp;
        }
      }
    }
  } else {
    int tg = tid & 255;
    int cc = tg & 127;
    int rh = tg >> 7;
    int eg = (e0 - 256) + grp * 128 + cc;
    float w0 = P[P_CW + eg * 4 + 0], w1 = P[P_CW + eg * 4 + 1];
    float w2 = P[P_CW + eg * 4 + 2], w3 = P[P_CW + eg * 4 + 3];
    float bb = P[P_CB + eg];
    int r0 = rh * 64;
    float x0 = (r0 >= 3) ? (float)sx[(r0 - 3) * 132 + cc] : 0.f;
    float x1 = (r0 >= 2) ? (float)sx[(r0 - 2) * 132 + cc] : 0.f;
    float x2 = (r0 >= 1) ? (float)sx[(r0 - 1) * 132 + cc] : 0.f;
    _Float16* xo = xch + (size_t)m0 * 384 + eg;
    for (int r = r0; r < r0 + 64; ++r) {
      float x3 = (float)sx[r * 132 + cc];
      float a = bb + w0 * x0 + w1 * x1 + w2 * x2 + w3 * x3;
      xo[(size_t)r * 384] = (_Float16)(a * __builtin_amdgcn_rcpf(1.f + __expf(-a)));
      x0 = x1; x1 = x2; x2 = x3;
    }
  }
}

// ---------------- K6 v13: SSD scan, 512 thr, head-parallel wave-groups ----------
// Group g (4 waves) = heads g*4..g*4+3. G computed ONCE by 8 waves (16 rows
// each), shared. Per-group Xt/ejs. Partial sumsq combined via LDS (reuses Ts).
__global__ __launch_bounds__(512) void k_ssd_v5(const _Float16* __restrict__ xch,
                                                const _Float16* __restrict__ zh,
                                                const float* __restrict__ dtb,
                                                const float* __restrict__ P,
                                                _Float16* __restrict__ ys,
                                                float* __restrict__ rr) {
  int seq = blockIdx.x;
  int tid = threadIdx.x;
  int lane = tid & 63, wv = tid >> 6;       // wv 0..7
  int grp = wv >> 2, wvl = wv & 3;
  int tg = tid & 255;
  int rsel = lane & 15, q = lane >> 4;
  __shared__ __align__(16) _Float16 G[128 * 128];    // 32 KB
  __shared__ __align__(16) _Float16 Xt[2][32 * 128]; // 16 KB
  __shared__ float dts[128 * 8];                     // 4 KB
  __shared__ float Ts[8 * 128];                      // 4 KB (reused for ssq combine)
  __shared__ float ejs[2][128];                      // 1 KB
  const _Float16* xb = xch + (size_t)seq * 49152;
  const _Float16* zb = zh + (size_t)seq * 32768;
  const float* dtp = dtb + (size_t)seq * 1024;

  for (int i = tid; i < 1024; i += 512) dts[i] = dtp[i];
  __syncthreads();
  if (tid < 8) {
    float a = 0.f;
    for (int l = 0; l < 128; ++l) { a += dts[l * 8 + tid]; Ts[tid * 128 + l] = a; }
  }

  // phase 1: G = C @ B^T — 8 waves, 16 rows each
  {
    f32x4 gacc[8];
#pragma unroll
    for (int cf = 0; cf < 8; ++cf) gacc[cf] = (f32x4){0.f, 0.f, 0.f, 0.f};
#pragma unroll
    for (int kk = 0; kk < 2; ++kk) {
      int l = wv * 16 + rsel;
      half8 a = *(const half8*)&xb[(size_t)l * 384 + 320 + kk * 32 + q * 8];
#pragma unroll
      for (int cf = 0; cf < 8; ++cf) {
        int j = cf * 16 + rsel;
        half8 b = *(const half8*)&xb[(size_t)j * 384 + 256 + kk * 32 + q * 8];
        gacc[cf] = __builtin_amdgcn_mfma_f32_16x16x32_f16(a, b, gacc[cf], 0, 0, 0);
      }
    }
#pragma unroll
    for (int r = 0; r < 4; ++r) {
      int l = wv * 16 + q * 4 + r;
#pragma unroll
      for (int cf = 0; cf < 8; ++cf) {
        int j = cf * 16 + rsel;
        G[l * 128 + (((j >> 3) ^ (l & 7)) << 3) + (j & 7)] = (_Float16)gacc[cf][r];
      }
    }
  }
  __syncthreads();

  float ssq[2][4];
#pragma unroll
  for (int rf = 0; rf < 2; ++rf)
#pragma unroll
    for (int r = 0; r < 4; ++r) ssq[rf][r] = 0.f;

  _Float16* yp = ys + (size_t)seq * 32768;
  for (int hh = 0; hh < 4; ++hh) {
    int h = grp * 4 + hh;
    float Ah = -__expf(P[P_ALOG + h]);
    float Dk = P[P_DSKIP + h];
    // stage Xt[grp] + ejs[grp] for this head (group's 256 threads)
    {
      int j = tg >> 1, ds = (tg & 1) * 16;
      float dtj = dts[j * 8 + h];
      half8 v0 = *(const half8*)&xb[(size_t)j * 384 + h * 32 + ds];
      half8 v1 = *(const half8*)&xb[(size_t)j * 384 + h * 32 + ds + 8];
#pragma unroll
      for (int e = 0; e < 8; ++e) {
        int d0 = ds + e, d1 = ds + 8 + e;
        Xt[grp][d0 * 128 + (((j >> 3) ^ (d0 & 7)) << 3) + (j & 7)] =
            (_Float16)((float)v0[e] * dtj);
        Xt[grp][d1 * 128 + (((j >> 3) ^ (d1 & 7)) << 3) + (j & 7)] =
            (_Float16)((float)v1[e] * dtj);
      }
      if (tg < 128) {
        float TE = Ts[h * 128 + ((tg >> 5) << 5) + 31];
        ejs[grp][tg] = __expf(Ah * (TE - Ts[h * 128 + tg]));
      }
    }
    __syncthreads();
    f32x4 acc[2][2];
#pragma unroll
    for (int rf = 0; rf < 2; ++rf)
#pragma unroll
      for (int cf = 0; cf < 2; ++cf) acc[rf][cf] = (f32x4){0.f, 0.f, 0.f, 0.f};
#pragma unroll
    for (int kk = 0; kk < 4; ++kk) {
      if (kk <= wvl) {
        int jb = kk * 32 + q * 8;
        int chk = kk * 4 + q;
        half8 a[2];
        if (kk == wvl) {
          float4 tj0 = *(const float4*)&Ts[h * 128 + jb];
          float4 tj1 = *(const float4*)&Ts[h * 128 + jb + 4];
          float tj[8] = {tj0.x, tj0.y, tj0.z, tj0.w, tj1.x, tj1.y, tj1.z, tj1.w};
#pragma unroll
          for (int rf = 0; rf < 2; ++rf) {
            int l = wvl * 32 + rf * 16 + rsel;
            half8 g = *(const half8*)&G[l * 128 + ((chk ^ (l & 7)) << 3)];
            float Tl = Ts[h * 128 + l];
            half8 w;
#pragma unroll
            for (int e = 0; e < 8; ++e) {
              int j = jb + e;
              float m = (j <= l) ? __expf(Ah * (Tl - tj[e])) : 0.f;
              w[e] = (_Float16)((float)g[e] * m);
            }
            a[rf] = w;
          }
        } else {
          float TE = Ts[h * 128 + kk * 32 + 31];
          float4 e0v = *(const float4*)&ejs[grp][jb];
          float4 e1v = *(const float4*)&ejs[grp][jb + 4];
          float ej[8] = {e0v.x, e0v.y, e0v.z, e0v.w, e1v.x, e1v.y, e1v.z, e1v.w};
#pragma unroll
          for (int rf = 0; rf < 2; ++rf) {
            int l = wvl * 32 + rf * 16 + rsel;
            half8 g = *(const half8*)&G[l * 128 + ((chk ^ (l & 7)) << 3)];
            float el = __expf(Ah * (Ts[h * 128 + l] - TE));
            half8 w;
#pragma unroll
            for (int e = 0; e < 8; ++e)
              w[e] = (_Float16)((float)g[e] * el * ej[e]);
            a[rf] = w;
          }
        }
#pragma unroll
        for (int cf = 0; cf < 2; ++cf) {
          int d = cf * 16 + rsel;
          half8 b = *(const half8*)&Xt[grp][d * 128 + ((chk ^ (d & 7)) << 3)];
          acc[0][cf] = __builtin_amdgcn_mfma_f32_16x16x32_f16(a[0], b, acc[0][cf], 0, 0, 0);
          acc[1][cf] = __builtin_amdgcn_mfma_f32_16x16x32_f16(a[1], b, acc[1][cf], 0, 0, 0);
        }
      }
    }
#pragma unroll
    for (int rf = 0; rf < 2; ++rf) {
      int lb = wvl * 32 + rf * 16 + q * 4;
#pragma unroll
      for (int cf = 0; cf < 2; ++cf) {
        int d = cf * 16 + rsel;
#pragma unroll
        for (int r = 0; r < 4; ++r) {
          int l = lb + r;
          float xv = (float)xb[(size_t)l * 384 + h * 32 + d];
          float zv = (float)zb[(size_t)l * 256 + h * 32 + d];
          float y = acc[rf][cf][r] + Dk * xv;
          float yg = y * (zv / (1.f + __expf(-zv)));
          ssq[rf][r] += yg * yg;
          yp[(size_t)l * 256 + h * 32 + d] = (_Float16)yg;
        }
      }
    }
    __syncthreads();
  }

  // combine partial sumsq: group partials into Ts[grp*128 + token], then rsqrt
#pragma unroll
  for (int rf = 0; rf < 2; ++rf) {
#pragma unroll
    for (int r = 0; r < 4; ++r) {
      float ss = ssq[rf][r];
      ss += __shfl_xor(ss, 1, 64);
      ss += __shfl_xor(ss, 2, 64);
      ss += __shfl_xor(ss, 4, 64);
      ss += __shfl_xor(ss, 8, 64);
      if (rsel == 0) Ts[grp * 128 + wvl * 32 + rf * 16 + q * 4 + r] = ss;
    }
  }
  __syncthreads();
  if (tid < 128) {
    float ss = Ts[tid] + Ts[128 + tid];
    rr[(size_t)seq * 128 + tid] = rsqrtf(ss * (1.f / 256.f) + 1e-5f);
  }
}

// ---------------- G2 v4: out = (ys * rr[l]) @ outwh^T (ng pre-folded) -----------
__global__ __launch_bounds__(256) void k_gemm2_v4(const _Float16* __restrict__ ysg,
                                                  const float* __restrict__ rr,
                                                  const _Float16* __restrict__ outwh,
                                                  float* __restrict__ dout,
                                                  int tok0) {
  __shared__ __align__(16) _Float16 lA[128 * 64];
  __shared__ __align__(16) _Float16 lB[64 * 64];
  int t0 = blockIdx.x * 64;
  int tid = threadIdx.x;
  int lane = tid & 63;
  int wv = tid >> 6;
  f32x4 acc[2][4];
#pragma unroll
  for (int rf = 0; rf < 2; ++rf)
#pragma unroll
    for (int cf = 0; cf < 4; ++cf) acc[rf][cf] = (f32x4){0.f, 0.f, 0.f, 0.f};

  int rsel = lane & 15, q = lane >> 4;
  for (int k0 = 0; k0 < 256; k0 += 64) {
    if (k0) __syncthreads();
#pragma unroll
    for (int p = 0; p < 4; ++p) {
      int idx = tid + 256 * p;
      int row = idx >> 3, ch = idx & 7;
      int dch = ch ^ (row & 7);
      *(half8*)&lA[row * 64 + dch * 8] =
          *(const half8*)&outwh[(size_t)row * 256 + k0 + ch * 8];
    }
#pragma unroll
    for (int p = 0; p < 2; ++p) {
      int idx = tid + 256 * p;
      int row = idx >> 3, ch = idx & 7;
      int dch = ch ^ (row & 7);
      float rv = rr[t0 + row];
      half8 v = *(const half8*)&ysg[(size_t)(t0 + row) * 256 + k0 + ch * 8];
      half8 o;
#pragma unroll
      for (int e = 0; e < 8; ++e) o[e] = (_Float16)((float)v[e] * rv);
      *(half8*)&lB[row * 64 + dch * 8] = o;
    }
    __syncthreads();
#pragma unroll
    for (int kk = 0; kk < 2; ++kk) {
      half8 a[2];
#pragma unroll
      for (int rf = 0; rf < 2; ++rf) {
        int row = wv * 32 + rf * 16 + rsel;
        int ch = (kk * 4 + q) ^ (row & 7);
        a[rf] = *(const half8*)&lA[row * 64 + ch * 8];
      }
#pragma unroll
      for (int cf = 0; cf < 4; ++cf) {
        int row = cf * 16 + rsel;
        int ch = (kk * 4 + q) ^ (row & 7);
        half8 b = *(const half8*)&lB[row * 64 + ch * 8];
        acc[0][cf] = __builtin_amdgcn_mfma_f32_16x16x32_f16(a[0], b, acc[0][cf], 0, 0, 0);
        acc[1][cf] = __builtin_amdgcn_mfma_f32_16x16x32_f16(a[1], b, acc[1][cf], 0, 0, 0);
      }
    }
  }

  int l0 = tok0 + t0;
  int b = l0 >> 14;
  int rem0 = l0 & 16383;
#pragma unroll
  for (int rf = 0; rf < 2; ++rf) {
    int cbase = wv * 32 + rf * 16 + q * 4;
#pragma unroll
    for (int cf = 0; cf < 4; ++cf) {
#pragma unroll
      for (int r = 0; r < 4; ++r) {
        dout[(size_t)(b * 128 + cbase + r) * 16384 + rem0 + cf * 16 + rsel] = acc[rf][cf][r];
      }
    }
  }
}

extern "C" void kernel_launch(void* const* d_in, const int* in_sizes, int n_in,
                              void* d_out, int out_size, void* d_ws, size_t ws_size,
                              hipStream_t stream) {
  const void* x      = d_in[0];
  const void* dww    = d_in[1];
  const void* gng    = d_in[2];
  const void* gnb    = d_in[3];
  const void* pww    = d_in[4];
  const void* pwb    = d_in[5];
  const void* wproj  = d_in[6];
  const void* cw     = d_in[7];
  const void* cb     = d_in[8];
  const void* dtbias = d_in[9];
  const void* alog   = d_in[10];
  const void* dskip  = d_in[11];
  const void* ng     = d_in[12];
  const void* outw   = d_in[13];
  float* out = (float*)d_out;

  char* ws = (char*)d_ws;
  float* gst        = (float*)(ws + 0);
  float* P          = (float*)(ws + 8192);
  _Float16* wprojh  = (_Float16*)(ws + 40960);
  _Float16* outwh   = (_Float16*)(ws + 372736);
  float* part       = (float*)(ws + 503808);      // 2048*128*4 = 1,048,576 B
  char* cbase       = ws + 1552384;

  // h1 (f16, 33.5 MB) lives in d_out's out_2d region (fully overwritten later).
  _Float16* h1h = (_Float16*)out;

  // Per-sequence chunk bytes:
  //   seq 32768 + zh 65536 + xch 98304 + dtb 4096 + ys 65536 + rr 512 = 266752.
  const int opts[11] = {1024, 512, 256, 128, 64, 32, 16, 8, 4, 2, 1};
  int CH = 1;
  for (int i = 0; i < 11; ++i) {
    if (1552384ull + (unsigned long long)opts[i] * 266752ull <= (unsigned long long)ws_size) {
      CH = opts[i];
      break;
    }
  }
  int NC = 1024 / CH;

  _Float16* seqh = (_Float16*)(cbase);
  _Float16* zh   = (_Float16*)(cbase + (size_t)CH * 32768);
  _Float16* xch  = (_Float16*)(cbase + (size_t)CH * 98304);
  float* dtbf    = (float*)(cbase + (size_t)CH * 196608);
  _Float16* ysh  = (_Float16*)(cbase + (size_t)CH * 200704);
  float* rrf     = (float*)(cbase + (size_t)CH * 266240);

  k_prep_all<<<128, 256, 0, stream>>>(dww, cw, cb, gng, gnb, pww, pwb, dtbias,
                                      alog, dskip, ng, wproj, outw, P, gst,
                                      wprojh, outwh);
  k_dwconv_v6<<<1024, 256, 0, stream>>>(x, gng, P, h1h, gst);
  k_gn_part<<<2048, 256, 0, stream>>>(h1h, gst, P, part);

  int M = CH * 128;
  for (int c = 0; c < NC; ++c) {
    int s0 = c * CH;
    k_deform_v5<<<CH, 256, 0, stream>>>(x, gng, part, P, seqh, out, s0);
    k_gemm1_v8<<<dim3(M / 128, 3), 512, 0, stream>>>(seqh, wprojh, P, zh, xch, dtbf);
    k_ssd_v5<<<CH, 512, 0, stream>>>(xch, zh, dtbf, P, ysh, rrf);
    k_gemm2_v4<<<dim3(M / 64), 256, 0, stream>>>(ysh, rrf, outwh, out, s0 * 128);
  }
}

// Round 20
// 449.045 us; speedup vs baseline: 1.0105x; 1.0105x over previous
//
#include <hip/hip_runtime.h>
#include <math.h>

// B=8, C=128, H=128, W=128, D_INNER=256, D_STATE=64, HEADDIM=32, NHEADS=8,
// D_CONV=4, GN_GROUPS=8, D_XBC=384, D_INPROJ=648.
// Inputs f32 (probed via gn_g word0). OUTPUT IS F32 (reference output dtype).
// d_out = [out_2d: 16,777,216 f32][offset: 131,072 f32].
// h1 (f16) is staged in d_out's out_2d region.
//
// R10 SSD matrix scan 679 -> R11 conv1d into gemm1 594 -> R14 gn_part 494 ->
// R15 gate into ssd 469 -> R17 factorized decay 468 -> R18 gemm1 BN=256 450 ->
// R19 ssd 512-thr head-groups REGRESSED (56us, occupancy still ~19%) 454.
// R20: REVERT ssd to v4 (48us, R18 state). Both occupancy experiments (R16
// cross-block, R19 in-block) show ssd residency capped ~2 blocks/CU; v4 is
// the measured optimum for this structure.

typedef _Float16 half8 __attribute__((ext_vector_type(8)));
typedef _Float16 half4 __attribute__((ext_vector_type(4)));
typedef float f32x4 __attribute__((ext_vector_type(4)));

__device__ __forceinline__ float b2f(unsigned short u) {
  return __uint_as_float(((unsigned int)u) << 16);
}
__device__ __forceinline__ bool in_is_f32(const void* gng) {
  return ((const unsigned int*)gng)[0] == 0x3F800000u;
}

#define P_DWW 0
#define P_CW 3200
#define P_CB 4736
#define P_GNG 5120
#define P_GNB 5248
#define P_PWW 5376
#define P_PWB 5504
#define P_DTB 5505
#define P_ALOG 5513
#define P_DSKIP 5521
#define P_NG 5529

// ---------------- P0: all prep in one launch ------------------------------------
__global__ void k_prep_all(const void* dww, const void* cw, const void* cb,
                           const void* gng, const void* gnb, const void* pww,
                           const void* pwb, const void* dtbias, const void* alog,
                           const void* dskip, const void* ng,
                           const void* wproj, const void* outw,
                           float* __restrict__ P, float* __restrict__ gst,
                           _Float16* __restrict__ wprojh, _Float16* __restrict__ outwh) {
  bool f = in_is_f32(gng);
  int stride = gridDim.x * blockDim.x;
  for (int i = blockIdx.x * blockDim.x + threadIdx.x; i < 98304; i += stride) {
    int row = i >> 7;
    float v = 0.f;
    if (row < 648) v = f ? ((const float*)wproj)[i] : b2f(((const unsigned short*)wproj)[i]);
    wprojh[i] = (_Float16)v;
  }
  for (int i = blockIdx.x * blockDim.x + threadIdx.x; i < 32768; i += stride) {
    int e = i & 255;
    float wv = f ? ((const float*)outw)[i] : b2f(((const unsigned short*)outw)[i]);
    float ngv = f ? ((const float*)ng)[e] : b2f(((const unsigned short*)ng)[e]);
    outwh[i] = (_Float16)(wv * ngv);
  }
  if (blockIdx.x == 0) {
    int tid = threadIdx.x;
    if (tid < 128) gst[tid] = 0.f;
    auto cvt = [&](const void* src, int n, int off) {
      for (int i = tid; i < n; i += 256)
        P[off + i] = f ? ((const float*)src)[i] : b2f(((const unsigned short*)src)[i]);
    };
    cvt(dww, 3200, P_DWW);
    cvt(cw, 1536, P_CW);
    cvt(cb, 384, P_CB);
    cvt(gng, 128, P_GNG);
    cvt(gnb, 128, P_GNB);
    cvt(pww, 128, P_PWW);
    cvt(pwb, 1, P_PWB);
    cvt(dtbias, 8, P_DTB);
    cvt(alog, 8, P_ALOG);
    cvt(dskip, 8, P_DSKIP);
    cvt(ng, 256, P_NG);
  }
}

// ---------------- K1 v6: depthwise 5x5 conv + group stats, NO LDS ---------------
__global__ __launch_bounds__(256) void k_dwconv_v6(const void* __restrict__ x,
                                                   const void* __restrict__ gng,
                                                   const float* __restrict__ P,
                                                   _Float16* __restrict__ h1h,
                                                   float* __restrict__ gst) {
  int bc = blockIdx.x;
  int b = bc >> 7, c = bc & 127;
  bool f32x = in_is_f32(gng);
  __shared__ float red[8];
  const float* xf = (const float*)x + (size_t)bc * 16384;
  const unsigned short* xb = (const unsigned short*)x + (size_t)bc * 16384;
  float w[25];
#pragma unroll
  for (int k = 0; k < 25; ++k) w[k] = P[P_DWW + c * 25 + k];

  int ox = (threadIdx.x & 31) * 4;   // 0..124
  int y0 = (threadIdx.x >> 5) * 16;  // 0..112
  float win[5][12];

  auto loadrow = [&](int gy, float* d) {
#pragma unroll
    for (int k = 0; k < 12; ++k) d[k] = 0.f;
    if (gy >= 0 && gy < 128) {
      if (f32x) {
        const float* rp = xf + gy * 128;
        if (ox >= 4) {
          float4 v = *(const float4*)(rp + ox - 4);
          d[0] = v.x; d[1] = v.y; d[2] = v.z; d[3] = v.w;
        }
        float4 v0 = *(const float4*)(rp + ox);
        d[4] = v0.x; d[5] = v0.y; d[6] = v0.z; d[7] = v0.w;
        if (ox < 124) {
          float4 v1 = *(const float4*)(rp + ox + 4);
          d[8] = v1.x; d[9] = v1.y; d[10] = v1.z; d[11] = v1.w;
        }
      } else {
        const unsigned short* rp = xb + gy * 128;
        if (ox >= 4) {
          ushort4 u = *(const ushort4*)(rp + ox - 4);
          d[0] = b2f(u.x); d[1] = b2f(u.y); d[2] = b2f(u.z); d[3] = b2f(u.w);
        }
        ushort4 u0 = *(const ushort4*)(rp + ox);
        d[4] = b2f(u0.x); d[5] = b2f(u0.y); d[6] = b2f(u0.z); d[7] = b2f(u0.w);
        if (ox < 124) {
          ushort4 u1 = *(const ushort4*)(rp + ox + 4);
          d[8] = b2f(u1.x); d[9] = b2f(u1.y); d[10] = b2f(u1.z); d[11] = b2f(u1.w);
        }
      }
    }
  };

#pragma unroll
  for (int i = 0; i < 4; ++i) loadrow(y0 - 2 + i, win[i]);

  float s = 0.f, sq = 0.f;
  _Float16* hp = h1h + (size_t)bc * 16384;
#pragma unroll
  for (int yo = 0; yo < 16; ++yo) {
    loadrow(y0 + yo + 2, win[(yo + 4) % 5]);
    float o4[4] = {0.f, 0.f, 0.f, 0.f};
#pragma unroll
    for (int ky = 0; ky < 5; ++ky) {
      const float* r = win[(yo + ky) % 5];
#pragma unroll
      for (int j = 0; j < 4; ++j)
#pragma unroll
        for (int kx = 0; kx < 5; ++kx)
          o4[j] += w[ky * 5 + kx] * r[j + kx + 2];
    }
    half4 oh;
#pragma unroll
    for (int j = 0; j < 4; ++j) {
      oh[j] = (_Float16)o4[j];
      s += o4[j]; sq += o4[j] * o4[j];
    }
    *(half4*)&hp[(y0 + yo) * 128 + ox] = oh;
  }

  for (int o = 32; o; o >>= 1) { s += __shfl_down(s, o, 64); sq += __shfl_down(sq, o, 64); }
  int wv = threadIdx.x >> 6;
  if ((threadIdx.x & 63) == 0) { red[wv] = s; red[4 + wv] = sq; }
  __syncthreads();
  if (threadIdx.x == 0) {
    float ts = red[0] + red[1] + red[2] + red[3];
    float tq = red[4] + red[5] + red[6] + red[7];
    int g = (b << 3) + (c >> 4);
    atomicAdd(&gst[g * 2], ts);
    atomicAdd(&gst[g * 2 + 1], tq);
  }
}

// ---------------- K3 v5: GN + GELU + 1x1 conv PARTIAL ---------------------------
__global__ __launch_bounds__(256) void k_gn_part(const _Float16* __restrict__ h1h,
                                                 const float* __restrict__ gst,
                                                 const float* __restrict__ P,
                                                 float* __restrict__ part) {
  int bh2 = blockIdx.x;
  int b = bh2 >> 8;
  int h = (bh2 & 255) >> 1;
  int half = bh2 & 1;
  int tid = threadIdx.x;
  int w = tid & 127;
  int sub = tid >> 7;
  __shared__ float ls[8];
  __shared__ float sacc[2][128];
  if (tid < 4) {
    const float invN = 1.f / 262144.f;
    int g = b * 8 + half * 4 + tid;
    float mean = gst[g * 2] * invN;
    float var = gst[g * 2 + 1] * invN - mean * mean;
    ls[tid * 2] = mean;
    ls[tid * 2 + 1] = rsqrtf(var + 1e-5f);
  }
  __syncthreads();
  int cbase = half * 64 + sub * 32;
  const _Float16* hb = h1h + (((size_t)(b * 128 + cbase)) * 128 + h) * 128 + w;
  float acc = 0.f;
#pragma unroll 4
  for (int ci = 0; ci < 32; ++ci) {
    int c = cbase + ci;
    float v = (float)hb[(size_t)ci * 16384];
    int lg = (sub * 32 + ci) >> 4;
    float nv = (v - ls[lg * 2]) * ls[lg * 2 + 1] * P[P_GNG + c] + P[P_GNB + c];
    float ge = 0.5f * nv * (1.f + erff(nv * 0.70710678118f));
    acc += ge * P[P_PWW + c];
  }
  sacc[sub][w] = acc;
  __syncthreads();
  if (sub == 0) part[(size_t)bh2 * 128 + w] = acc + sacc[1][w];
}

// ---------------- K4 v5: deform (combines gn partials + tanh), 2 ch/iter --------
__global__ __launch_bounds__(256) void k_deform_v5(const void* __restrict__ x,
                                                   const void* __restrict__ gng,
                                                   const float* __restrict__ part,
                                                   const float* __restrict__ P,
                                                   _Float16* __restrict__ seqc,
                                                   float* __restrict__ dout,
                                                   int s0) {
  int bh = s0 + blockIdx.x;
  int b = bh >> 7, h = bh & 127;
  int tid = threadIdx.x;
  int w = tid & 127;
  int half = tid >> 7;
  bool f32x = in_is_f32(gng);
  __shared__ float t[128 * 129];
  float ofv = tanhf(part[(size_t)bh * 256 + w] + part[(size_t)bh * 256 + 128 + w] +
                    P[P_PWB]) * 8.0f;
  if (half == 0) dout[16777216 + bh * 128 + w] = ofv;
  float gy = -1.f + (2.f / 127.f) * (float)h + ofv * (2.f / 127.f);
  gy = fminf(fmaxf(gy, -1.f), 1.f);
  float py = (gy + 1.f) * 0.5f * 127.f;
  py = fminf(fmaxf(py, 0.f), 127.f);
  float y0f = floorf(py);
  float wy = py - y0f;
  int y0 = (int)y0f;
  int y1 = min(y0 + 1, 127);
  const float* xfb = (const float*)x + (size_t)b * 128 * 16384;
  const unsigned short* xbb = (const unsigned short*)x + (size_t)b * 128 * 16384;
  int c0 = half * 64;
  for (int i = 0; i < 64; i += 2) {
    int ca = c0 + i, cb2 = c0 + i + 1;
    size_t a0 = (size_t)ca * 16384 + y0 * 128 + w;
    size_t a1 = (size_t)ca * 16384 + y1 * 128 + w;
    size_t b0 = (size_t)cb2 * 16384 + y0 * 128 + w;
    size_t b1 = (size_t)cb2 * 16384 + y1 * 128 + w;
    float va0, va1, vb0, vb1;
    if (f32x) { va0 = xfb[a0]; va1 = xfb[a1]; vb0 = xfb[b0]; vb1 = xfb[b1]; }
    else      { va0 = b2f(xbb[a0]); va1 = b2f(xbb[a1]);
                vb0 = b2f(xbb[b0]); vb1 = b2f(xbb[b1]); }
    t[ca * 129 + w] = va0 + wy * (va1 - va0);
    t[cb2 * 129 + w] = vb0 + wy * (vb1 - vb0);
  }
  __syncthreads();
  int c2 = tid & 127;
  int lb = (tid >> 7) * 64;
  _Float16* sp = seqc + (size_t)blockIdx.x * 16384;
  for (int i = 0; i < 64; ++i) {
    int l = lb + i;
    sp[l * 128 + c2] = (_Float16)t[c2 * 129 + l];
  }
}

// ---------------- G1 v8: BN=256, 512 thr, shared A staging, dt fast path --------
__global__ __launch_bounds__(512) void k_gemm1_v8(const _Float16* __restrict__ seqh,
                                                  const _Float16* __restrict__ wprojh,
                                                  const float* __restrict__ P,
                                                  _Float16* __restrict__ zh,
                                                  _Float16* __restrict__ xch,
                                                  float* __restrict__ dtb) {
  __shared__ __align__(16) _Float16 lds[33792];   // lA(8192)|lB(16384) or sx 2x16896
  _Float16* lA = lds;
  _Float16* lB = lds + 8192;
  int m0 = blockIdx.x * 128;
  int e0 = blockIdx.y * 256;
  int tid = threadIdx.x;
  int lane = tid & 63;
  int wv = tid >> 6;          // 0..7
  int grp = tid >> 8;         // 0/1
  int wvl = wv & 3;           // wave within group
  int rsel = lane & 15, q = lane >> 4;
  bool isz = (e0 == 0);
  bool isdt = (e0 == 512) && (grp == 1);

  f32x4 acc[2][8];
#pragma unroll
  for (int rf = 0; rf < 2; ++rf)
#pragma unroll
    for (int cf = 0; cf < 8; ++cf) acc[rf][cf] = (f32x4){0.f, 0.f, 0.f, 0.f};

  for (int k0 = 0; k0 < 128; k0 += 64) {
    if (k0) __syncthreads();
#pragma unroll
    for (int p = 0; p < 2; ++p) {
      int idx = tid + 512 * p;
      int row = idx >> 3, ch = idx & 7;
      int dch = ch ^ (row & 7);
      *(half8*)&lA[row * 64 + dch * 8] =
          *(const half8*)&seqh[(size_t)(m0 + row) * 128 + k0 + ch * 8];
    }
#pragma unroll
    for (int p = 0; p < 4; ++p) {
      int idx = tid + 512 * p;
      int row = idx >> 3, ch = idx & 7;
      int dch = ch ^ (row & 7);
      *(half8*)&lB[row * 64 + dch * 8] =
          *(const half8*)&wprojh[(size_t)(e0 + row) * 128 + k0 + ch * 8];
    }
    __syncthreads();
#pragma unroll
    for (int kk = 0; kk < 2; ++kk) {
      half8 a[2];
#pragma unroll
      for (int rf = 0; rf < 2; ++rf) {
        int row = wvl * 32 + rf * 16 + rsel;
        int ch = (kk * 4 + q) ^ (row & 7);
        a[rf] = *(const half8*)&lA[row * 64 + ch * 8];
      }
#pragma unroll
      for (int cf = 0; cf < 8; ++cf) {
        if (isdt && cf > 0) continue;
        int row = grp * 128 + cf * 16 + rsel;
        int ch = (kk * 4 + q) ^ (row & 7);
        half8 b = *(const half8*)&lB[row * 64 + ch * 8];
        acc[0][cf] = __builtin_amdgcn_mfma_f32_16x16x32_f16(a[0], b, acc[0][cf], 0, 0, 0);
        acc[1][cf] = __builtin_amdgcn_mfma_f32_16x16x32_f16(a[1], b, acc[1][cf], 0, 0, 0);
      }
    }
  }

  __syncthreads();
  _Float16* sx = lds + grp * 16896;   // [128][132]
  if (!isz && !isdt) {
#pragma unroll
    for (int rf = 0; rf < 2; ++rf) {
#pragma unroll
      for (int r = 0; r < 4; ++r) {
        int row = wvl * 32 + rf * 16 + q * 4 + r;
#pragma unroll
        for (int cf = 0; cf < 8; ++cf)
          sx[row * 132 + cf * 16 + rsel] = (_Float16)acc[rf][cf][r];
      }
    }
  }
  __syncthreads();

  if (isz) {
#pragma unroll
    for (int rf = 0; rf < 2; ++rf) {
      int mb = m0 + wvl * 32 + rf * 16 + q * 4;
#pragma unroll
      for (int cf = 0; cf < 8; ++cf) {
        _Float16* pz = zh + (size_t)mb * 256 + grp * 128 + cf * 16 + rsel;
#pragma unroll
        for (int r = 0; r < 4; ++r) pz[(size_t)r * 256] = (_Float16)acc[rf][cf][r];
      }
    }
  } else if (isdt) {
#pragma unroll
    for (int rf = 0; rf < 2; ++rf) {
      int mb = m0 + wvl * 32 + rf * 16 + q * 4;
      if (rsel < 8) {
        float bias = P[P_DTB + rsel];
#pragma unroll
        for (int r = 0; r < 4; ++r) {
          float dv = acc[rf][0][r] + bias;
          float sp = (dv > 20.f) ? dv : log1pf(__expf(dv));
          dtb[(size_t)(mb + r) * 8 + rsel] = sp;
        }
      }
    }
  } else {
    int tg = tid & 255;
    int cc = tg & 127;
    int rh = tg >> 7;
    int eg = (e0 - 256) + grp * 128 + cc;
    float w0 = P[P_CW + eg * 4 + 0], w1 = P[P_CW + eg * 4 + 1];
    float w2 = P[P_CW + eg * 4 + 2], w3 = P[P_CW + eg * 4 + 3];
    float bb = P[P_CB + eg];
    int r0 = rh * 64;
    float x0 = (r0 >= 3) ? (float)sx[(r0 - 3) * 132 + cc] : 0.f;
    float x1 = (r0 >= 2) ? (float)sx[(r0 - 2) * 132 + cc] : 0.f;
    float x2 = (r0 >= 1) ? (float)sx[(r0 - 1) * 132 + cc] : 0.f;
    _Float16* xo = xch + (size_t)m0 * 384 + eg;
    for (int r = r0; r < r0 + 64; ++r) {
      float x3 = (float)sx[r * 132 + cc];
      float a = bb + w0 * x0 + w1 * x1 + w2 * x2 + w3 * x3;
      xo[(size_t)r * 384] = (_Float16)(a * __builtin_amdgcn_rcpf(1.f + __expf(-a)));
      x0 = x1; x1 = x2; x2 = x3;
    }
  }
}

// ---------------- K6 v12: SSD scan, factorized decay + tile skip (REVERTED) -----
__global__ __launch_bounds__(256) void k_ssd_v4(const _Float16* __restrict__ xch,
                                                const _Float16* __restrict__ zh,
                                                const float* __restrict__ dtb,
                                                const float* __restrict__ P,
                                                _Float16* __restrict__ ys,
                                                float* __restrict__ rr) {
  int seq = blockIdx.x;
  int tid = threadIdx.x;
  int lane = tid & 63, wv = tid >> 6;
  int rsel = lane & 15, q = lane >> 4;
  __shared__ __align__(16) _Float16 G[128 * 128];
  __shared__ __align__(16) _Float16 Xt[32 * 128];
  __shared__ float dts[128 * 8];
  __shared__ float Ts[8 * 128];
  __shared__ float ejs[128];
  const _Float16* xb = xch + (size_t)seq * 49152;
  const _Float16* zb = zh + (size_t)seq * 32768;
  const float* dtp = dtb + (size_t)seq * 1024;

  for (int i = tid; i < 1024; i += 256) dts[i] = dtp[i];
  __syncthreads();
  if (tid < 8) {
    float a = 0.f;
    for (int l = 0; l < 128; ++l) { a += dts[l * 8 + tid]; Ts[tid * 128 + l] = a; }
  }

  // phase 1: G = C @ B^T
  f32x4 gacc[2][8];
#pragma unroll
  for (int rf = 0; rf < 2; ++rf)
#pragma unroll
    for (int cf = 0; cf < 8; ++cf) gacc[rf][cf] = (f32x4){0.f, 0.f, 0.f, 0.f};
#pragma unroll
  for (int kk = 0; kk < 2; ++kk) {
    half8 a[2];
#pragma unroll
    for (int rf = 0; rf < 2; ++rf) {
      int l = wv * 32 + rf * 16 + rsel;
      a[rf] = *(const half8*)&xb[(size_t)l * 384 + 320 + kk * 32 + q * 8];
    }
#pragma unroll
    for (int cf = 0; cf < 8; ++cf) {
      int j = cf * 16 + rsel;
      half8 b = *(const half8*)&xb[(size_t)j * 384 + 256 + kk * 32 + q * 8];
      gacc[0][cf] = __builtin_amdgcn_mfma_f32_16x16x32_f16(a[0], b, gacc[0][cf], 0, 0, 0);
      gacc[1][cf] = __builtin_amdgcn_mfma_f32_16x16x32_f16(a[1], b, gacc[1][cf], 0, 0, 0);
    }
  }
#pragma unroll
  for (int rf = 0; rf < 2; ++rf) {
#pragma unroll
    for (int r = 0; r < 4; ++r) {
      int l = wv * 32 + rf * 16 + q * 4 + r;
#pragma unroll
      for (int cf = 0; cf < 8; ++cf) {
        int j = cf * 16 + rsel;
        G[l * 128 + (((j >> 3) ^ (l & 7)) << 3) + (j & 7)] = (_Float16)gacc[rf][cf][r];
      }
    }
  }
  __syncthreads();

  float ssq[2][4];
#pragma unroll
  for (int rf = 0; rf < 2; ++rf)
#pragma unroll
    for (int r = 0; r < 4; ++r) ssq[rf][r] = 0.f;

  _Float16* yp = ys + (size_t)seq * 32768;
  for (int h = 0; h < 8; ++h) {
    float Ah = -__expf(P[P_ALOG + h]);
    float Dk = P[P_DSKIP + h];
    {
      int j = tid >> 1, ds = (tid & 1) * 16;
      float dtj = dts[j * 8 + h];
      half8 v0 = *(const half8*)&xb[(size_t)j * 384 + h * 32 + ds];
      half8 v1 = *(const half8*)&xb[(size_t)j * 384 + h * 32 + ds + 8];
#pragma unroll
      for (int e = 0; e < 8; ++e) {
        int d0 = ds + e, d1 = ds + 8 + e;
        Xt[d0 * 128 + (((j >> 3) ^ (d0 & 7)) << 3) + (j & 7)] = (_Float16)((float)v0[e] * dtj);
        Xt[d1 * 128 + (((j >> 3) ^ (d1 & 7)) << 3) + (j & 7)] = (_Float16)((float)v1[e] * dtj);
      }
      if (tid < 128) {
        float TE = Ts[h * 128 + ((tid >> 5) << 5) + 31];
        ejs[tid] = __expf(Ah * (TE - Ts[h * 128 + tid]));
      }
    }
    __syncthreads();
    f32x4 acc[2][2];
#pragma unroll
    for (int rf = 0; rf < 2; ++rf)
#pragma unroll
      for (int cf = 0; cf < 2; ++cf) acc[rf][cf] = (f32x4){0.f, 0.f, 0.f, 0.f};
#pragma unroll
    for (int kk = 0; kk < 4; ++kk) {
      if (kk <= wv) {
        int jb = kk * 32 + q * 8;
        int chk = kk * 4 + q;
        half8 a[2];
        if (kk == wv) {
          float4 tj0 = *(const float4*)&Ts[h * 128 + jb];
          float4 tj1 = *(const float4*)&Ts[h * 128 + jb + 4];
          float tj[8] = {tj0.x, tj0.y, tj0.z, tj0.w, tj1.x, tj1.y, tj1.z, tj1.w};
#pragma unroll
          for (int rf = 0; rf < 2; ++rf) {
            int l = wv * 32 + rf * 16 + rsel;
            half8 g = *(const half8*)&G[l * 128 + ((chk ^ (l & 7)) << 3)];
            float Tl = Ts[h * 128 + l];
            half8 w;
#pragma unroll
            for (int e = 0; e < 8; ++e) {
              int j = jb + e;
              float m = (j <= l) ? __expf(Ah * (Tl - tj[e])) : 0.f;
              w[e] = (_Float16)((float)g[e] * m);
            }
            a[rf] = w;
          }
        } else {
          float TE = Ts[h * 128 + kk * 32 + 31];
          float4 e0v = *(const float4*)&ejs[jb];
          float4 e1v = *(const float4*)&ejs[jb + 4];
          float ej[8] = {e0v.x, e0v.y, e0v.z, e0v.w, e1v.x, e1v.y, e1v.z, e1v.w};
#pragma unroll
          for (int rf = 0; rf < 2; ++rf) {
            int l = wv * 32 + rf * 16 + rsel;
            half8 g = *(const half8*)&G[l * 128 + ((chk ^ (l & 7)) << 3)];
            float el = __expf(Ah * (Ts[h * 128 + l] - TE));
            half8 w;
#pragma unroll
            for (int e = 0; e < 8; ++e)
              w[e] = (_Float16)((float)g[e] * el * ej[e]);
            a[rf] = w;
          }
        }
#pragma unroll
        for (int cf = 0; cf < 2; ++cf) {
          int d = cf * 16 + rsel;
          half8 b = *(const half8*)&Xt[d * 128 + ((chk ^ (d & 7)) << 3)];
          acc[0][cf] = __builtin_amdgcn_mfma_f32_16x16x32_f16(a[0], b, acc[0][cf], 0, 0, 0);
          acc[1][cf] = __builtin_amdgcn_mfma_f32_16x16x32_f16(a[1], b, acc[1][cf], 0, 0, 0);
        }
      }
    }
#pragma unroll
    for (int rf = 0; rf < 2; ++rf) {
      int lb = wv * 32 + rf * 16 + q * 4;
#pragma unroll
      for (int cf = 0; cf < 2; ++cf) {
        int d = cf * 16 + rsel;
#pragma unroll
        for (int r = 0; r < 4; ++r) {
          int l = lb + r;
          float xv = (float)xb[(size_t)l * 384 + h * 32 + d];
          float zv = (float)zb[(size_t)l * 256 + h * 32 + d];
          float y = acc[rf][cf][r] + Dk * xv;
          float yg = y * (zv / (1.f + __expf(-zv)));
          ssq[rf][r] += yg * yg;
          yp[(size_t)l * 256 + h * 32 + d] = (_Float16)yg;
        }
      }
    }
    __syncthreads();
  }

  float* rp = rr + (size_t)seq * 128;
#pragma unroll
  for (int rf = 0; rf < 2; ++rf) {
#pragma unroll
    for (int r = 0; r < 4; ++r) {
      float ss = ssq[rf][r];
      ss += __shfl_xor(ss, 1, 64);
      ss += __shfl_xor(ss, 2, 64);
      ss += __shfl_xor(ss, 4, 64);
      ss += __shfl_xor(ss, 8, 64);
      if (rsel == 0) rp[wv * 32 + rf * 16 + q * 4 + r] = rsqrtf(ss * (1.f / 256.f) + 1e-5f);
    }
  }
}

// ---------------- G2 v4: out = (ys * rr[l]) @ outwh^T (ng pre-folded) -----------
__global__ __launch_bounds__(256) void k_gemm2_v4(const _Float16* __restrict__ ysg,
                                                  const float* __restrict__ rr,
                                                  const _Float16* __restrict__ outwh,
                                                  float* __restrict__ dout,
                                                  int tok0) {
  __shared__ __align__(16) _Float16 lA[128 * 64];
  __shared__ __align__(16) _Float16 lB[64 * 64];
  int t0 = blockIdx.x * 64;
  int tid = threadIdx.x;
  int lane = tid & 63;
  int wv = tid >> 6;
  f32x4 acc[2][4];
#pragma unroll
  for (int rf = 0; rf < 2; ++rf)
#pragma unroll
    for (int cf = 0; cf < 4; ++cf) acc[rf][cf] = (f32x4){0.f, 0.f, 0.f, 0.f};

  int rsel = lane & 15, q = lane >> 4;
  for (int k0 = 0; k0 < 256; k0 += 64) {
    if (k0) __syncthreads();
#pragma unroll
    for (int p = 0; p < 4; ++p) {
      int idx = tid + 256 * p;
      int row = idx >> 3, ch = idx & 7;
      int dch = ch ^ (row & 7);
      *(half8*)&lA[row * 64 + dch * 8] =
          *(const half8*)&outwh[(size_t)row * 256 + k0 + ch * 8];
    }
#pragma unroll
    for (int p = 0; p < 2; ++p) {
      int idx = tid + 256 * p;
      int row = idx >> 3, ch = idx & 7;
      int dch = ch ^ (row & 7);
      float rv = rr[t0 + row];
      half8 v = *(const half8*)&ysg[(size_t)(t0 + row) * 256 + k0 + ch * 8];
      half8 o;
#pragma unroll
      for (int e = 0; e < 8; ++e) o[e] = (_Float16)((float)v[e] * rv);
      *(half8*)&lB[row * 64 + dch * 8] = o;
    }
    __syncthreads();
#pragma unroll
    for (int kk = 0; kk < 2; ++kk) {
      half8 a[2];
#pragma unroll
      for (int rf = 0; rf < 2; ++rf) {
        int row = wv * 32 + rf * 16 + rsel;
        int ch = (kk * 4 + q) ^ (row & 7);
        a[rf] = *(const half8*)&lA[row * 64 + ch * 8];
      }
#pragma unroll
      for (int cf = 0; cf < 4; ++cf) {
        int row = cf * 16 + rsel;
        int ch = (kk * 4 + q) ^ (row & 7);
        half8 b = *(const half8*)&lB[row * 64 + ch * 8];
        acc[0][cf] = __builtin_amdgcn_mfma_f32_16x16x32_f16(a[0], b, acc[0][cf], 0, 0, 0);
        acc[1][cf] = __builtin_amdgcn_mfma_f32_16x16x32_f16(a[1], b, acc[1][cf], 0, 0, 0);
      }
    }
  }

  int l0 = tok0 + t0;
  int b = l0 >> 14;
  int rem0 = l0 & 16383;
#pragma unroll
  for (int rf = 0; rf < 2; ++rf) {
    int cbase = wv * 32 + rf * 16 + q * 4;
#pragma unroll
    for (int cf = 0; cf < 4; ++cf) {
#pragma unroll
      for (int r = 0; r < 4; ++r) {
        dout[(size_t)(b * 128 + cbase + r) * 16384 + rem0 + cf * 16 + rsel] = acc[rf][cf][r];
      }
    }
  }
}

extern "C" void kernel_launch(void* const* d_in, const int* in_sizes, int n_in,
                              void* d_out, int out_size, void* d_ws, size_t ws_size,
                              hipStream_t stream) {
  const void* x      = d_in[0];
  const void* dww    = d_in[1];
  const void* gng    = d_in[2];
  const void* gnb    = d_in[3];
  const void* pww    = d_in[4];
  const void* pwb    = d_in[5];
  const void* wproj  = d_in[6];
  const void* cw     = d_in[7];
  const void* cb     = d_in[8];
  const void* dtbias = d_in[9];
  const void* alog   = d_in[10];
  const void* dskip  = d_in[11];
  const void* ng     = d_in[12];
  const void* outw   = d_in[13];
  float* out = (float*)d_out;

  char* ws = (char*)d_ws;
  float* gst        = (float*)(ws + 0);
  float* P          = (float*)(ws + 8192);
  _Float16* wprojh  = (_Float16*)(ws + 40960);
  _Float16* outwh   = (_Float16*)(ws + 372736);
  float* part       = (float*)(ws + 503808);      // 2048*128*4 = 1,048,576 B
  char* cbase       = ws + 1552384;

  // h1 (f16, 33.5 MB) lives in d_out's out_2d region (fully overwritten later).
  _Float16* h1h = (_Float16*)out;

  // Per-sequence chunk bytes:
  //   seq 32768 + zh 65536 + xch 98304 + dtb 4096 + ys 65536 + rr 512 = 266752.
  const int opts[11] = {1024, 512, 256, 128, 64, 32, 16, 8, 4, 2, 1};
  int CH = 1;
  for (int i = 0; i < 11; ++i) {
    if (1552384ull + (unsigned long long)opts[i] * 266752ull <= (unsigned long long)ws_size) {
      CH = opts[i];
      break;
    }
  }
  int NC = 1024 / CH;

  _Float16* seqh = (_Float16*)(cbase);
  _Float16* zh   = (_Float16*)(cbase + (size_t)CH * 32768);
  _Float16* xch  = (_Float16*)(cbase + (size_t)CH * 98304);
  float* dtbf    = (float*)(cbase + (size_t)CH * 196608);
  _Float16* ysh  = (_Float16*)(cbase + (size_t)CH * 200704);
  float* rrf     = (float*)(cbase + (size_t)CH * 266240);

  k_prep_all<<<128, 256, 0, stream>>>(dww, cw, cb, gng, gnb, pww, pwb, dtbias,
                                      alog, dskip, ng, wproj, outw, P, gst,
                                      wprojh, outwh);
  k_dwconv_v6<<<1024, 256, 0, stream>>>(x, gng, P, h1h, gst);
  k_gn_part<<<2048, 256, 0, stream>>>(h1h, gst, P, part);

  int M = CH * 128;
  for (int c = 0; c < NC; ++c) {
    int s0 = c * CH;
    k_deform_v5<<<CH, 256, 0, stream>>>(x, gng, part, P, seqh, out, s0);
    k_gemm1_v8<<<dim3(M / 128, 3), 512, 0, stream>>>(seqh, wprojh, P, zh, xch, dtbf);
    k_ssd_v4<<<CH, 256, 0, stream>>>(xch, zh, dtbf, P, ysh, rrf);
    k_gemm2_v4<<<dim3(M / 64), 256, 0, stream>>>(ysh, rrf, outwh, out, s0 * 128);
  }
}